// Round 11
// baseline (227.807 us; speedup 1.0000x reference)
//
#include <hip/hip_runtime.h>
#include <cmath>

// CrossAttention: B=4, N=4096, M=1024, QD=320, CD=768, ID=512, H=8, Dh=64
// fp32 I/O; bf16 MFMA internals, fp32 accumulate.
// r11: flash = within-block key-split (2 q-halves x 2 key-halves per 256-thr
// block), 32-key dbuf tiles, LDS epilogue combine; gemm_kv/gemm_out = r9.
constexpr int BATCH  = 4;
constexpr int SEQ_N  = 4096;
constexpr int SEQ_M  = 1024;
constexpr int QD     = 320;
constexpr int CD     = 768;
constexpr int ID     = 512;
constexpr float QFOLD = 0.125f * 1.44269504f;   // SCALE*log2e folded into Wq
constexpr float EK2F  = -8.0f * 1.44269504f;    // fixed softmax shift (log2 dom)

typedef __bf16 bf16x8 __attribute__((ext_vector_type(8)));
typedef __bf16 bf16x4 __attribute__((ext_vector_type(4)));
typedef float  f32x4  __attribute__((ext_vector_type(4)));

__device__ __forceinline__ void gload_lds16(const __bf16* g, __bf16* l) {
    __builtin_amdgcn_global_load_lds(
        (const __attribute__((address_space(1))) void*)g,
        (__attribute__((address_space(3))) void*)l, 16, 0, 0);
}

// ---------------------------------------------------------------------------
// One dispatch: fp32->bf16 for x/ctx (blocks 0..4095) + weight transpose/cvt
// (blocks 4096..5183).  Wq pre-scaled by QFOLD.  (r9-verified)
// ---------------------------------------------------------------------------
__global__ __launch_bounds__(256)
void cvt_all(const float* __restrict__ x, const float* __restrict__ ctx,
             const float* __restrict__ Wq, const float* __restrict__ Wk,
             const float* __restrict__ Wv, const float* __restrict__ Wo,
             __bf16* __restrict__ xb, __bf16* __restrict__ ctxb,
             __bf16* __restrict__ WqT, __bf16* __restrict__ WkT,
             __bf16* __restrict__ WvT, __bf16* __restrict__ WoT) {
    __shared__ float tile[32][33];
    int bid = blockIdx.x;
    if (bid < 4096) {
        constexpr int NX8 = SEQ_N * BATCH * QD / 8;   // 655360
        int i = bid * 256 + threadIdx.x;
        const float* s; __bf16* d; int j;
        if (i < NX8) { s = x; d = xb; j = i; }
        else         { s = ctx; d = ctxb; j = i - NX8; }
        const float4* sp = reinterpret_cast<const float4*>(s) + (size_t)j * 2;
        float4 a = sp[0], b = sp[1];
        bf16x8 o = { (__bf16)a.x, (__bf16)a.y, (__bf16)a.z, (__bf16)a.w,
                     (__bf16)b.x, (__bf16)b.y, (__bf16)b.z, (__bf16)b.w };
        reinterpret_cast<bf16x8*>(d)[j] = o;
        return;
    }
    int wb = bid - 4096;
    const float* W; __bf16* WT; int K, N, tid; float scl = 1.0f;
    if (wb < 160)      { W = Wq; WT = WqT; K = 320; N = 512; tid = wb; scl = QFOLD; }
    else if (wb < 544) { W = Wk; WT = WkT; K = 768; N = 512; tid = wb - 160; }
    else if (wb < 928) { W = Wv; WT = WvT; K = 768; N = 512; tid = wb - 544; }
    else               { W = Wo; WT = WoT; K = 512; N = 320; tid = wb - 928; }
    int kt = K / 32;
    int k0 = (tid % kt) * 32, n0 = (tid / kt) * 32;
    int tc = threadIdx.x & 31, tr = threadIdx.x >> 5;
#pragma unroll
    for (int p = 0; p < 4; ++p)
        tile[p * 8 + tr][tc] = W[(size_t)(k0 + p * 8 + tr) * N + n0 + tc];
    __syncthreads();
#pragma unroll
    for (int p = 0; p < 4; ++p)
        WT[(size_t)(n0 + p * 8 + tr) * K + k0 + tc] = (__bf16)(tile[tc][p * 8 + tr] * scl);
}

// ---------------------------------------------------------------------------
// KV projection (r9-exact): 64x64 tiles, BK=64 dbuf, XOR chunk swizzle,
// operand-swapped MFMA.  y<8 -> Kb row-major; >=8 -> Vt via LDS transpose.
// ---------------------------------------------------------------------------
__global__ __launch_bounds__(256)
void gemm_kv(const __bf16* __restrict__ A, const __bf16* __restrict__ BT,
             __bf16* __restrict__ Kb, __bf16* __restrict__ Vt, int M, int K) {
    __shared__ __attribute__((aligned(16))) __bf16 sA[2][64][64];
    __shared__ __attribute__((aligned(16))) __bf16 sB[2][64][64];

    const int t = threadIdx.x;
    const int wave = t >> 6, lane = t & 63;
    const int q = lane >> 4, c = lane & 15;
    const int wm = wave >> 1, wn = wave & 1;
    const int row0 = blockIdx.x * 64, col0 = blockIdx.y * 64;
    const int srow = lane >> 3, sch = lane & 7;
    const int fch = sch ^ srow;

    auto stage = [&](int buf, int k0) {
#pragma unroll
        for (int i = 0; i < 2; ++i) {
            int r = wave * 16 + i * 8;
            gload_lds16(A + (size_t)(row0 + r + srow) * K + k0 + fch * 8,
                        &sA[buf][r][0] + lane * 8);
            gload_lds16(BT + (size_t)(col0 + r + srow) * K + k0 + fch * 8,
                        &sB[buf][r][0] + lane * 8);
        }
    };

    f32x4 acc[2][2] = {};
    stage(0, 0);
    const int iters = K >> 6;
    for (int it = 0; it < iters; ++it) {
        const int p = it & 1;
        __syncthreads();
        if (it + 1 < iters) stage(p ^ 1, (it + 1) * 64);
#pragma unroll
        for (int ks = 0; ks < 2; ++ks) {
            const int so = ((ks * 4 + q) ^ (c & 7)) * 8;
            bf16x8 am[2], bn[2];
#pragma unroll
            for (int i = 0; i < 2; ++i)
                am[i] = *reinterpret_cast<const bf16x8*>(&sA[p][wm * 32 + i * 16 + c][0] + so);
#pragma unroll
            for (int j = 0; j < 2; ++j)
                bn[j] = *reinterpret_cast<const bf16x8*>(&sB[p][wn * 32 + j * 16 + c][0] + so);
#pragma unroll
            for (int i = 0; i < 2; ++i)
#pragma unroll
                for (int j = 0; j < 2; ++j)
                    acc[i][j] = __builtin_amdgcn_mfma_f32_16x16x32_bf16(bn[j], am[i], acc[i][j], 0, 0, 0);
        }
    }

    if (blockIdx.y < 8) {
#pragma unroll
        for (int i = 0; i < 2; ++i)
#pragma unroll
            for (int j = 0; j < 2; ++j) {
                int mrow = row0 + wm * 32 + i * 16 + c;
                int ncol = col0 + wn * 32 + j * 16 + q * 4;
                bf16x4 v = { (__bf16)acc[i][j][0], (__bf16)acc[i][j][1],
                             (__bf16)acc[i][j][2], (__bf16)acc[i][j][3] };
                *reinterpret_cast<bf16x4*>(&Kb[(size_t)mrow * 512 + ncol]) = v;
            }
    } else {
        __bf16* ldsT = (__bf16*)sA;   // 64 x 72
        __syncthreads();
#pragma unroll
        for (int i = 0; i < 2; ++i)
#pragma unroll
            for (int j = 0; j < 2; ++j) {
                int ml = wm * 32 + i * 16 + c;
                int dl = wn * 32 + j * 16 + q * 4;
#pragma unroll
                for (int r = 0; r < 4; ++r)
                    ldsT[(dl + r) * 72 + ml] = (__bf16)acc[i][j][r];
            }
        __syncthreads();
        int b = row0 >> 10, m0 = row0 & 1023;
        int h = (col0 - 512) >> 6;
        int d = t >> 2, ch = t & 3;
        __bf16* dst = Vt + (((size_t)((b * 8 + h) * 64 + d)) << 10) + m0 + ch * 16;
        const __bf16* src = &ldsT[d * 72 + ch * 16];
        *reinterpret_cast<bf16x8*>(dst)     = *reinterpret_cast<const bf16x8*>(src);
        *reinterpret_cast<bf16x8*>(dst + 8) = *reinterpret_cast<const bf16x8*>(src + 8);
    }
}

// ---------------------------------------------------------------------------
// Flash attention v6: within-block key-split.  256-thr block = 128 queries.
// Wave w: queries (w&1)*64 (qt=4), keys (w>>1)*512 in 16 dbuf'd 32-key tiles.
// Fused Q-projection prologue (4-way split by query-half x d-half).
// Fixed-shift softmax exp2(s+EK2F in C-init); l accumulated in VALU with
// quad-shuffle reduce.  Epilogue: kh=1 waves dump O,l to LDS; kh=0 waves
// combine (+), normalize, store.  LDS 52 KB -> 3 blocks/CU; grid 1024 blocks
// -> 12 waves/CU (vs r9's 8).
// ---------------------------------------------------------------------------
__global__ __launch_bounds__(256, 3)
void flash_attn(const __bf16* __restrict__ xb, const __bf16* __restrict__ WqT,
                const __bf16* __restrict__ Kb, const __bf16* __restrict__ Vt,
                __bf16* __restrict__ AO) {
    // layout (bf16 elems): [0,8192) KV buf0 (sK 4096 | sV 4096),
    // [8192,16384) KV buf1, [16384,26624) sPT 4 x [64][40].
    // prologue overlays: sX [128][64] @0, sW [64][64] @8192, sQ [128][72] @16384.
    // epilogue overlays (f32): dumpO 2x4096 @0, dumpL 2x64 @f32-idx 8192.
    __shared__ __attribute__((aligned(16))) __bf16 smem[26624];

    const int t = threadIdx.x;
    const int wave = t >> 6, lane = t & 63;
    const int q = lane >> 4, c = lane & 15;
    const int qh = wave & 1, kh = wave >> 1;
    const int bh = blockIdx.y;
    const int b = bh >> 3, h = bh & 7;
    const int n0 = blockIdx.x * 128;
    const int srow = lane >> 3, sch = lane & 7;
    const int fch = sch ^ srow;

    // ---- Prologue: Q^T[64 d][128 q]; wave computes (qh, dh=kh) quadrant ---
    f32x4 accQ[2][4] = {};   // [dt][qt]
    {
        __bf16* sX = smem;            // [128][64]
        __bf16* sW = smem + 8192;     // [64][64]
        for (int k0 = 0; k0 < QD; k0 += 64) {
            __syncthreads();
#pragma unroll
            for (int i = 0; i < 4; ++i) {
                int r = wave * 32 + i * 8 + srow;
                gload_lds16(xb + (size_t)(b * SEQ_N + n0 + r) * QD + k0 + fch * 8,
                            sX + (wave * 32 + i * 8) * 64 + lane * 8);
            }
#pragma unroll
            for (int i = 0; i < 2; ++i) {
                int r = wave * 16 + i * 8 + srow;
                gload_lds16(WqT + (size_t)(h * 64 + r) * QD + k0 + fch * 8,
                            sW + (wave * 16 + i * 8) * 64 + lane * 8);
            }
            __syncthreads();
#pragma unroll
            for (int ks = 0; ks < 2; ++ks) {
                const int so = ((ks * 4 + q) ^ (c & 7)) * 8;
                bf16x8 aw[2], bx[4];
#pragma unroll
                for (int dt = 0; dt < 2; ++dt)
                    aw[dt] = *reinterpret_cast<const bf16x8*>(sW + (kh * 32 + dt * 16 + c) * 64 + so);
#pragma unroll
                for (int qt = 0; qt < 4; ++qt)
                    bx[qt] = *reinterpret_cast<const bf16x8*>(sX + (qh * 64 + qt * 16 + c) * 64 + so);
#pragma unroll
                for (int dt = 0; dt < 2; ++dt)
#pragma unroll
                    for (int qt = 0; qt < 4; ++qt)
                        accQ[dt][qt] = __builtin_amdgcn_mfma_f32_16x16x32_bf16(aw[dt], bx[qt], accQ[dt][qt], 0, 0, 0);
            }
        }
    }
    __syncthreads();
    // C-layout -> shared sQ [128 q][72] (rows = query, cols = d)
    __bf16* sQ = smem + 16384;
#pragma unroll
    for (int dt = 0; dt < 2; ++dt)
#pragma unroll
        for (int qt = 0; qt < 4; ++qt) {
            bf16x4 v = { (__bf16)accQ[dt][qt][0], (__bf16)accQ[dt][qt][1],
                         (__bf16)accQ[dt][qt][2], (__bf16)accQ[dt][qt][3] };
            *reinterpret_cast<bf16x4*>(sQ + (qh * 64 + qt * 16 + c) * 72 + kh * 32 + dt * 16 + q * 4) = v;
        }
    __syncthreads();
    bf16x8 aq[4][2];
#pragma unroll
    for (int qt = 0; qt < 4; ++qt)
#pragma unroll
        for (int ks = 0; ks < 2; ++ks)
            aq[qt][ks] = *reinterpret_cast<const bf16x8*>(sQ + (qh * 64 + qt * 16 + c) * 72 + ks * 32 + q * 8);
    __syncthreads();   // sQ region -> sPT reuse

    // ---- Main loop: 16 dbuf'd 32-key tiles per key-half -------------------
    auto stageKV = [&](int p, int m0) {
        __bf16* sK = smem + p * 8192;           // [64][64]: rows 0-31 kh0, 32-63 kh1
        __bf16* sV = smem + p * 8192 + 4096;    // [128][32]: rows 0-63 kh0, 64-127 kh1
        if (wave < 2) {
#pragma unroll
            for (int i = 0; i < 4; ++i) {
                int r = wave * 32 + i * 8 + srow;
                int mg = (r >> 5) * 512 + m0 + (r & 31);
                gload_lds16(Kb + (size_t)(b * SEQ_M + mg) * ID + h * 64 + fch * 8,
                            sK + (wave * 32 + i * 8) * 64 + lane * 8);
            }
        } else {
            int v = wave - 2;
            int sr2 = lane >> 2, sc2 = lane & 3;
#pragma unroll
            for (int i = 0; i < 4; ++i) {
                int rr = v * 64 + i * 16 + sr2;
                int d = rr & 63, st = rr >> 6;
                int f2 = sc2 ^ ((rr >> 1) & 3);
                gload_lds16(Vt + (((size_t)((b * 8 + h) * 64 + d)) << 10) + st * 512 + m0 + f2 * 8,
                            sV + (v * 64 + i * 16) * 32 + lane * 8);
            }
        }
    };

    f32x4 accO[4][4] = {};   // [qt][nt]
    float l4[4] = {};
    __bf16* sPTw = smem + 16384 + wave * 2560;  // [64][40]

    stageKV(0, 0);
    for (int mt = 0; mt < 16; ++mt) {
        const int p = mt & 1;
        __syncthreads();
        if (mt + 1 < 16) stageKV(p ^ 1, (mt + 1) * 32);
        const __bf16* sK = smem + p * 8192 + kh * 2048;
        const __bf16* sV = smem + p * 8192 + 4096 + kh * 2048;

        // S^T = K * Q^T + EK2F
        f32x4 s[4][2];
#pragma unroll
        for (int qt = 0; qt < 4; ++qt)
#pragma unroll
            for (int ct = 0; ct < 2; ++ct)
                s[qt][ct] = f32x4{ EK2F, EK2F, EK2F, EK2F };
#pragma unroll
        for (int ks = 0; ks < 2; ++ks) {
            const int so = ((ks * 4 + q) ^ (c & 7)) * 8;
#pragma unroll
            for (int ct = 0; ct < 2; ++ct) {
                bf16x8 ak = *reinterpret_cast<const bf16x8*>(sK + (ct * 16 + c) * 64 + so);
#pragma unroll
                for (int qt = 0; qt < 4; ++qt)
                    s[qt][ct] = __builtin_amdgcn_mfma_f32_16x16x32_bf16(ak, aq[qt][ks], s[qt][ct], 0, 0, 0);
            }
        }

        // p = exp2(s); VALU l accumulation; packed b64 sPT writes
#pragma unroll
        for (int qt = 0; qt < 4; ++qt)
#pragma unroll
            for (int ct = 0; ct < 2; ++ct) {
                float p0 = exp2f(s[qt][ct][0]);
                float p1 = exp2f(s[qt][ct][1]);
                float p2 = exp2f(s[qt][ct][2]);
                float p3 = exp2f(s[qt][ct][3]);
                l4[qt] += (p0 + p1) + (p2 + p3);
                bf16x4 w = { (__bf16)p0, (__bf16)p1, (__bf16)p2, (__bf16)p3 };
                *reinterpret_cast<bf16x4*>(sPTw + (qt * 16 + c) * 40 + ct * 16 + q * 4) = w;
            }

        // O^T += V^T * P^T (k-dim = 32 keys, one MFMA step)
        const int sov = (q ^ ((c >> 1) & 3)) * 8;
        bf16x8 bp[4];
#pragma unroll
        for (int qt = 0; qt < 4; ++qt)
            bp[qt] = *reinterpret_cast<const bf16x8*>(sPTw + (qt * 16 + c) * 40 + q * 8);
#pragma unroll
        for (int nt = 0; nt < 4; ++nt) {
            bf16x8 av = *reinterpret_cast<const bf16x8*>(sV + (nt * 16 + c) * 32 + sov);
#pragma unroll
            for (int qt = 0; qt < 4; ++qt)
                accO[qt][nt] = __builtin_amdgcn_mfma_f32_16x16x32_bf16(av, bp[qt], accO[qt][nt], 0, 0, 0);
        }
    }

    // ---- Epilogue: quad-reduce l, cross-wave combine, store --------------
#pragma unroll
    for (int qt = 0; qt < 4; ++qt) {
        l4[qt] += __shfl_xor(l4[qt], 16, 64);
        l4[qt] += __shfl_xor(l4[qt], 32, 64);
    }
    __syncthreads();   // all KV/sPT LDS reads complete before dump overlay
    float* dO = (float*)smem;                // 2 x 4096 f32 (32 KB)
    float* dL = (float*)smem + 8192;         // 2 x 64 f32
    if (kh == 1) {
#pragma unroll
        for (int qt = 0; qt < 4; ++qt)
#pragma unroll
            for (int nt = 0; nt < 4; ++nt)
#pragma unroll
                for (int r = 0; r < 4; ++r)
                    dO[qh * 4096 + qt * 1024 + (nt * 16 + q * 4 + r) * 16 + c] = accO[qt][nt][r];
        if (q == 0)
#pragma unroll
            for (int qt = 0; qt < 4; ++qt)
                dL[qh * 64 + qt * 16 + c] = l4[qt];
    }
    __syncthreads();
    if (kh == 0) {
#pragma unroll
        for (int qt = 0; qt < 4; ++qt) {
            float inv = 1.0f / (l4[qt] + dL[qh * 64 + qt * 16 + c]);
            size_t rowb = (size_t)(b * SEQ_N + n0 + qh * 64 + qt * 16 + c) * ID + h * 64;
#pragma unroll
            for (int nt = 0; nt < 4; ++nt) {
                float o0 = accO[qt][nt][0] + dO[qh * 4096 + qt * 1024 + (nt * 16 + q * 4 + 0) * 16 + c];
                float o1 = accO[qt][nt][1] + dO[qh * 4096 + qt * 1024 + (nt * 16 + q * 4 + 1) * 16 + c];
                float o2 = accO[qt][nt][2] + dO[qh * 4096 + qt * 1024 + (nt * 16 + q * 4 + 2) * 16 + c];
                float o3 = accO[qt][nt][3] + dO[qh * 4096 + qt * 1024 + (nt * 16 + q * 4 + 3) * 16 + c];
                bf16x4 v = { (__bf16)(o0 * inv), (__bf16)(o1 * inv),
                             (__bf16)(o2 * inv), (__bf16)(o3 * inv) };
                *reinterpret_cast<bf16x4*>(&AO[rowb + nt * 16 + q * 4]) = v;
            }
        }
    }
}

// ---------------------------------------------------------------------------
// Output projection (r9-exact): out = AO @ WoT^T + bias, fp32 out.
// 128x64 tiles (grid 640), wave 64x32, BK=64 dbuf, XOR swizzle.
// ---------------------------------------------------------------------------
__global__ __launch_bounds__(256)
void gemm_out(const __bf16* __restrict__ A, const __bf16* __restrict__ BT,
              const float* __restrict__ bias, float* __restrict__ C,
              int M, int N, int K) {
    __shared__ __attribute__((aligned(16))) __bf16 sA[2][128][64];
    __shared__ __attribute__((aligned(16))) __bf16 sB[2][64][64];

    const int t = threadIdx.x;
    const int wave = t >> 6, lane = t & 63;
    const int q = lane >> 4, c = lane & 15;
    const int wm = wave >> 1, wn = wave & 1;
    const int row0 = blockIdx.x * 128, col0 = blockIdx.y * 64;
    const int srow = lane >> 3, sch = lane & 7;
    const int fch = sch ^ srow;

    auto stage = [&](int buf, int k0) {
#pragma unroll
        for (int i = 0; i < 4; ++i) {
            int r = wave * 32 + i * 8;
            gload_lds16(A + (size_t)(row0 + r + srow) * K + k0 + fch * 8,
                        &sA[buf][r][0] + lane * 8);
        }
#pragma unroll
        for (int i = 0; i < 2; ++i) {
            int r = wave * 16 + i * 8;
            gload_lds16(BT + (size_t)(col0 + r + srow) * K + k0 + fch * 8,
                        &sB[buf][r][0] + lane * 8);
        }
    };

    f32x4 acc[4][2] = {};
    stage(0, 0);
    const int iters = K >> 6;
    for (int it = 0; it < iters; ++it) {
        const int p = it & 1;
        __syncthreads();
        if (it + 1 < iters) stage(p ^ 1, (it + 1) * 64);
#pragma unroll
        for (int ks = 0; ks < 2; ++ks) {
            const int so = ((ks * 4 + q) ^ (c & 7)) * 8;
            bf16x8 am[4], bn[2];
#pragma unroll
            for (int i = 0; i < 4; ++i)
                am[i] = *reinterpret_cast<const bf16x8*>(&sA[p][wm * 64 + i * 16 + c][0] + so);
#pragma unroll
            for (int j = 0; j < 2; ++j)
                bn[j] = *reinterpret_cast<const bf16x8*>(&sB[p][wn * 32 + j * 16 + c][0] + so);
#pragma unroll
            for (int i = 0; i < 4; ++i)
#pragma unroll
                for (int j = 0; j < 2; ++j)
                    acc[i][j] = __builtin_amdgcn_mfma_f32_16x16x32_bf16(bn[j], am[i], acc[i][j], 0, 0, 0);
        }
    }

#pragma unroll
    for (int i = 0; i < 4; ++i)
#pragma unroll
        for (int j = 0; j < 2; ++j) {
            int mrow = row0 + wm * 64 + i * 16 + c;
            int ncol = col0 + wn * 32 + j * 16 + q * 4;
            float4 v = { acc[i][j][0] + bias[ncol + 0],
                         acc[i][j][1] + bias[ncol + 1],
                         acc[i][j][2] + bias[ncol + 2],
                         acc[i][j][3] + bias[ncol + 3] };
            *reinterpret_cast<float4*>(&C[(size_t)mrow * N + ncol]) = v;
        }
}

// ---------------------------------------------------------------------------
extern "C" void kernel_launch(void* const* d_in, const int* in_sizes, int n_in,
                              void* d_out, int out_size, void* d_ws, size_t ws_size,
                              hipStream_t stream) {
    const float* x   = (const float*)d_in[0];
    const float* ctx = (const float*)d_in[1];
    const float* Wq  = (const float*)d_in[2];
    const float* Wk  = (const float*)d_in[3];
    const float* Wv  = (const float*)d_in[4];
    const float* Wo  = (const float*)d_in[5];
    const float* bo  = (const float*)d_in[6];
    float* out = (float*)d_out;

    char* ws = (char*)d_ws;
    __bf16* xb   = (__bf16*)(ws + 0);                 // 16384x320 (stays live)
    __bf16* ctxb = (__bf16*)(ws + 10485760);          // 4096x768
    __bf16* AO   = (__bf16*)(ws + 16777216);          // 16384x512
    __bf16* Kb   = (__bf16*)(ws + 33554432);          // 4096x512
    __bf16* Vt   = (__bf16*)(ws + 37748736);          // (32,64,1024)
    __bf16* WqT  = (__bf16*)(ws + 41943040);          // 512x320 (pre-scaled)
    __bf16* WkT  = (__bf16*)(ws + 42270720);          // 512x768 \ adjacent
    __bf16* WvT  = (__bf16*)(ws + 43057152);          // 512x768 / = 1024x768
    __bf16* WoT  = (__bf16*)(ws + 43843584);          // 320x512

    const int MX = BATCH * SEQ_N;   // 16384
    const int MC = BATCH * SEQ_M;   // 4096

    cvt_all<<<dim3(5184), dim3(256), 0, stream>>>(x, ctx, Wq, Wk, Wv, Wo,
                                                  xb, ctxb, WqT, WkT, WvT, WoT);

    // fused K+V projection (r9: 64x64 tiles; y<8 -> Kb, y>=8 -> Vt)
    gemm_kv<<<dim3(MC / 64, 16), dim3(256), 0, stream>>>(ctxb, WkT, Kb, Vt, MC, CD);

    // flash with fused Q-projection (128 queries x 2 key-halves per block)
    flash_attn<<<dim3(SEQ_N / 128, 32), dim3(256), 0, stream>>>(xb, WqT, Kb, Vt, AO);

    // output projection + bias (fp32 out)
    gemm_out<<<dim3(MX / 128, QD / 64), dim3(256), 0, stream>>>(AO, WoT, bo, out, MX, QD, ID);
}

// Round 12
// 184.389 us; speedup vs baseline: 1.2355x; 1.2355x over previous
//
#include <hip/hip_runtime.h>
#include <cmath>

// CrossAttention: B=4, N=4096, M=1024, QD=320, CD=768, ID=512, H=8, Dh=64
// fp32 I/O; bf16 MFMA internals, fp32 accumulate.
// r12 = r9-exact (best known) with flash l-accumulation moved from ones-MFMA
// to VALU adds + epilogue shuffle reduce (-11% flash MFMA issue).
constexpr int BATCH  = 4;
constexpr int SEQ_N  = 4096;
constexpr int SEQ_M  = 1024;
constexpr int QD     = 320;
constexpr int CD     = 768;
constexpr int ID     = 512;
constexpr float QFOLD = 0.125f * 1.44269504f;   // SCALE*log2e folded into Wq
constexpr float EK2F  = -8.0f * 1.44269504f;    // fixed softmax shift (log2 dom)

typedef __bf16 bf16x8 __attribute__((ext_vector_type(8)));
typedef __bf16 bf16x4 __attribute__((ext_vector_type(4)));
typedef __bf16 bf16x2 __attribute__((ext_vector_type(2)));
typedef float  f32x4  __attribute__((ext_vector_type(4)));

__device__ __forceinline__ void gload_lds16(const __bf16* g, __bf16* l) {
    __builtin_amdgcn_global_load_lds(
        (const __attribute__((address_space(1))) void*)g,
        (__attribute__((address_space(3))) void*)l, 16, 0, 0);
}

// ---------------------------------------------------------------------------
// One dispatch: fp32->bf16 for x/ctx (blocks 0..4095) + weight transpose/cvt
// (blocks 4096..5183).  Wq pre-scaled by QFOLD.  (r9-verified)
// ---------------------------------------------------------------------------
__global__ __launch_bounds__(256)
void cvt_all(const float* __restrict__ x, const float* __restrict__ ctx,
             const float* __restrict__ Wq, const float* __restrict__ Wk,
             const float* __restrict__ Wv, const float* __restrict__ Wo,
             __bf16* __restrict__ xb, __bf16* __restrict__ ctxb,
             __bf16* __restrict__ WqT, __bf16* __restrict__ WkT,
             __bf16* __restrict__ WvT, __bf16* __restrict__ WoT) {
    __shared__ float tile[32][33];
    int bid = blockIdx.x;
    if (bid < 4096) {
        constexpr int NX8 = SEQ_N * BATCH * QD / 8;   // 655360
        int i = bid * 256 + threadIdx.x;
        const float* s; __bf16* d; int j;
        if (i < NX8) { s = x; d = xb; j = i; }
        else         { s = ctx; d = ctxb; j = i - NX8; }
        const float4* sp = reinterpret_cast<const float4*>(s) + (size_t)j * 2;
        float4 a = sp[0], b = sp[1];
        bf16x8 o = { (__bf16)a.x, (__bf16)a.y, (__bf16)a.z, (__bf16)a.w,
                     (__bf16)b.x, (__bf16)b.y, (__bf16)b.z, (__bf16)b.w };
        reinterpret_cast<bf16x8*>(d)[j] = o;
        return;
    }
    int wb = bid - 4096;
    const float* W; __bf16* WT; int K, N, tid; float scl = 1.0f;
    if (wb < 160)      { W = Wq; WT = WqT; K = 320; N = 512; tid = wb; scl = QFOLD; }
    else if (wb < 544) { W = Wk; WT = WkT; K = 768; N = 512; tid = wb - 160; }
    else if (wb < 928) { W = Wv; WT = WvT; K = 768; N = 512; tid = wb - 544; }
    else               { W = Wo; WT = WoT; K = 512; N = 320; tid = wb - 928; }
    int kt = K / 32;
    int k0 = (tid % kt) * 32, n0 = (tid / kt) * 32;
    int tc = threadIdx.x & 31, tr = threadIdx.x >> 5;
#pragma unroll
    for (int p = 0; p < 4; ++p)
        tile[p * 8 + tr][tc] = W[(size_t)(k0 + p * 8 + tr) * N + n0 + tc];
    __syncthreads();
#pragma unroll
    for (int p = 0; p < 4; ++p)
        WT[(size_t)(n0 + p * 8 + tr) * K + k0 + tc] = (__bf16)(tile[tc][p * 8 + tr] * scl);
}

// ---------------------------------------------------------------------------
// KV projection (r9-exact): 64x64 tiles, BK=64 dbuf, XOR chunk swizzle,
// operand-swapped MFMA.  y<8 -> Kb row-major; >=8 -> Vt via LDS transpose.
// ---------------------------------------------------------------------------
__global__ __launch_bounds__(256)
void gemm_kv(const __bf16* __restrict__ A, const __bf16* __restrict__ BT,
             __bf16* __restrict__ Kb, __bf16* __restrict__ Vt, int M, int K) {
    __shared__ __attribute__((aligned(16))) __bf16 sA[2][64][64];
    __shared__ __attribute__((aligned(16))) __bf16 sB[2][64][64];

    const int t = threadIdx.x;
    const int wave = t >> 6, lane = t & 63;
    const int q = lane >> 4, c = lane & 15;
    const int wm = wave >> 1, wn = wave & 1;
    const int row0 = blockIdx.x * 64, col0 = blockIdx.y * 64;
    const int srow = lane >> 3, sch = lane & 7;
    const int fch = sch ^ srow;

    auto stage = [&](int buf, int k0) {
#pragma unroll
        for (int i = 0; i < 2; ++i) {
            int r = wave * 16 + i * 8;
            gload_lds16(A + (size_t)(row0 + r + srow) * K + k0 + fch * 8,
                        &sA[buf][r][0] + lane * 8);
            gload_lds16(BT + (size_t)(col0 + r + srow) * K + k0 + fch * 8,
                        &sB[buf][r][0] + lane * 8);
        }
    };

    f32x4 acc[2][2] = {};
    stage(0, 0);
    const int iters = K >> 6;
    for (int it = 0; it < iters; ++it) {
        const int p = it & 1;
        __syncthreads();
        if (it + 1 < iters) stage(p ^ 1, (it + 1) * 64);
#pragma unroll
        for (int ks = 0; ks < 2; ++ks) {
            const int so = ((ks * 4 + q) ^ (c & 7)) * 8;
            bf16x8 am[2], bn[2];
#pragma unroll
            for (int i = 0; i < 2; ++i)
                am[i] = *reinterpret_cast<const bf16x8*>(&sA[p][wm * 32 + i * 16 + c][0] + so);
#pragma unroll
            for (int j = 0; j < 2; ++j)
                bn[j] = *reinterpret_cast<const bf16x8*>(&sB[p][wn * 32 + j * 16 + c][0] + so);
#pragma unroll
            for (int i = 0; i < 2; ++i)
#pragma unroll
                for (int j = 0; j < 2; ++j)
                    acc[i][j] = __builtin_amdgcn_mfma_f32_16x16x32_bf16(bn[j], am[i], acc[i][j], 0, 0, 0);
        }
    }

    if (blockIdx.y < 8) {
#pragma unroll
        for (int i = 0; i < 2; ++i)
#pragma unroll
            for (int j = 0; j < 2; ++j) {
                int mrow = row0 + wm * 32 + i * 16 + c;
                int ncol = col0 + wn * 32 + j * 16 + q * 4;
                bf16x4 v = { (__bf16)acc[i][j][0], (__bf16)acc[i][j][1],
                             (__bf16)acc[i][j][2], (__bf16)acc[i][j][3] };
                *reinterpret_cast<bf16x4*>(&Kb[(size_t)mrow * 512 + ncol]) = v;
            }
    } else {
        __bf16* ldsT = (__bf16*)sA;   // 64 x 72
        __syncthreads();
#pragma unroll
        for (int i = 0; i < 2; ++i)
#pragma unroll
            for (int j = 0; j < 2; ++j) {
                int ml = wm * 32 + i * 16 + c;
                int dl = wn * 32 + j * 16 + q * 4;
#pragma unroll
                for (int r = 0; r < 4; ++r)
                    ldsT[(dl + r) * 72 + ml] = (__bf16)acc[i][j][r];
            }
        __syncthreads();
        int b = row0 >> 10, m0 = row0 & 1023;
        int h = (col0 - 512) >> 6;
        int d = t >> 2, ch = t & 3;
        __bf16* dst = Vt + (((size_t)((b * 8 + h) * 64 + d)) << 10) + m0 + ch * 16;
        const __bf16* src = &ldsT[d * 72 + ch * 16];
        *reinterpret_cast<bf16x8*>(dst)     = *reinterpret_cast<const bf16x8*>(src);
        *reinterpret_cast<bf16x8*>(dst + 8) = *reinterpret_cast<const bf16x8*>(src + 8);
    }
}

// ---------------------------------------------------------------------------
// Flash attention (r9 structure): block = (b,h) x 256 queries; 4 waves x 64
// queries (qt=4).  Fused Q-projection prologue.  64-key tiles, dbuf sK/sV
// (one barrier/tile).  S^T = K*Q^T with EK2F in MFMA C-init; p = exp2(s);
// l accumulated in VALU during exp (r12: replaces ones-MFMA) with epilogue
// shuffle reduce over the 4 lanes sharing a query column.
// LDS: 16384 (KV dbuf) + 18432 (sPT) elems = 69632 B -> 2 blocks/CU (= grid).
// ---------------------------------------------------------------------------
__global__ __launch_bounds__(256, 2)
void flash_attn(const __bf16* __restrict__ xb, const __bf16* __restrict__ WqT,
                const __bf16* __restrict__ Kb, const __bf16* __restrict__ Vt,
                __bf16* __restrict__ AO) {
    __shared__ __attribute__((aligned(16))) __bf16 smem[34816];
    // main: sK(buf)=smem+buf*8192, sV(buf)=smem+buf*8192+4096; sPT=smem+16384
    // prologue: sX=smem (256x64), sW=smem+16384 (64x64)
    __bf16* sPT = smem + 16384;          // [4 waves][64][72]

    const int t = threadIdx.x;
    const int wave = t >> 6, lane = t & 63;
    const int q = lane >> 4, c = lane & 15;
    const int bh = blockIdx.y;
    const int b = bh >> 3, h = bh & 7;
    const int n0 = blockIdx.x * 256;
    const int srow = lane >> 3, sch = lane & 7;
    const int fch = sch ^ srow;

    // ---- Prologue: Q^T[64 d][256 q] = WqT_h @ xb^T, 5 staged BK=64 iters --
    f32x4 accQ[4][4] = {};   // [dt][qt]
    {
        __bf16* sX = smem;
        __bf16* sW = smem + 16384;
        for (int k0 = 0; k0 < QD; k0 += 64) {
            __syncthreads();
#pragma unroll
            for (int i = 0; i < 8; ++i) {
                int r = wave * 64 + i * 8;
                gload_lds16(xb + (size_t)(b * SEQ_N + n0 + r + srow) * QD + k0 + fch * 8,
                            sX + r * 64 + lane * 8);
            }
#pragma unroll
            for (int i = 0; i < 2; ++i) {
                int r = wave * 16 + i * 8;
                gload_lds16(WqT + (size_t)(h * 64 + r + srow) * QD + k0 + fch * 8,
                            sW + r * 64 + lane * 8);
            }
            __syncthreads();
#pragma unroll
            for (int ks = 0; ks < 2; ++ks) {
                const int so = ((ks * 4 + q) ^ (c & 7)) * 8;
                bf16x8 aw[4], bx[4];
#pragma unroll
                for (int dt = 0; dt < 4; ++dt)
                    aw[dt] = *reinterpret_cast<const bf16x8*>(sW + (dt * 16 + c) * 64 + so);
#pragma unroll
                for (int qt = 0; qt < 4; ++qt)
                    bx[qt] = *reinterpret_cast<const bf16x8*>(sX + (wave * 64 + qt * 16 + c) * 64 + so);
#pragma unroll
                for (int dt = 0; dt < 4; ++dt)
#pragma unroll
                    for (int qt = 0; qt < 4; ++qt)
                        accQ[dt][qt] = __builtin_amdgcn_mfma_f32_16x16x32_bf16(aw[dt], bx[qt], accQ[dt][qt], 0, 0, 0);
            }
        }
    }
    __syncthreads();   // all prologue LDS reads consumed before region reuse

    // C-layout -> per-wave LDS slice -> B-layout register frags
    __bf16* sQw = sPT + wave * 4608;     // [64][72]
#pragma unroll
    for (int dt = 0; dt < 4; ++dt)
#pragma unroll
        for (int qt = 0; qt < 4; ++qt) {
            bf16x2 w0 = { (__bf16)accQ[dt][qt][0], (__bf16)accQ[dt][qt][1] };
            bf16x2 w1 = { (__bf16)accQ[dt][qt][2], (__bf16)accQ[dt][qt][3] };
            __bf16* pr = sQw + (qt * 16 + c) * 72 + dt * 16 + q * 4;
            *reinterpret_cast<bf16x2*>(pr)     = w0;
            *reinterpret_cast<bf16x2*>(pr + 2) = w1;
        }
    bf16x8 aq[4][2];
#pragma unroll
    for (int qt = 0; qt < 4; ++qt)
#pragma unroll
        for (int ks = 0; ks < 2; ++ks)
            aq[qt][ks] = *reinterpret_cast<const bf16x8*>(sQw + (qt * 16 + c) * 72 + ks * 32 + q * 8);

    // ---- Main loop: dbuf KV, one barrier per tile -------------------------
    auto stageKV = [&](int buf, int m0) {
        __bf16* sK = smem + buf * 8192;
        __bf16* sV = smem + buf * 8192 + 4096;
#pragma unroll
        for (int i = 0; i < 2; ++i) {
            int r = wave * 16 + i * 8;
            gload_lds16(Kb + (size_t)(b * SEQ_M + m0 + r + srow) * ID + h * 64 + fch * 8,
                        sK + r * 64 + lane * 8);
            gload_lds16(Vt + (((size_t)((b * 8 + h) * 64 + r + srow)) << 10) + m0 + fch * 8,
                        sV + r * 64 + lane * 8);
        }
    };

    f32x4 accO[4][4] = {};   // [qt][nt]
    float l4[4] = {};        // per-lane partial softmax denominators

    stageKV(0, 0);
    constexpr int TILES = SEQ_M / 64;   // 16
    for (int mt = 0; mt < TILES; ++mt) {
        const int p = mt & 1;
        __syncthreads();                 // buf p staged (barrier drains vmcnt)
        if (mt + 1 < TILES) stageKV(p ^ 1, (mt + 1) * 64);
        const __bf16* sK = smem + p * 8192;
        const __bf16* sV = smem + p * 8192 + 4096;

        // S^T = K * Q^T + EK2F (shift folded into C-init)
        f32x4 s[4][4];
#pragma unroll
        for (int qt = 0; qt < 4; ++qt)
#pragma unroll
            for (int ct = 0; ct < 4; ++ct)
                s[qt][ct] = f32x4{ EK2F, EK2F, EK2F, EK2F };
#pragma unroll
        for (int ks = 0; ks < 2; ++ks) {
            const int so = ((ks * 4 + q) ^ (c & 7)) * 8;
#pragma unroll
            for (int ct = 0; ct < 4; ++ct) {
                bf16x8 ak = *reinterpret_cast<const bf16x8*>(sK + (ct * 16 + c) * 64 + so);
#pragma unroll
                for (int qt = 0; qt < 4; ++qt)
                    s[qt][ct] = __builtin_amdgcn_mfma_f32_16x16x32_bf16(ak, aq[qt][ks], s[qt][ct], 0, 0, 0);
            }
        }

        // p = exp2(s); l accumulated in VALU; packed-pair writes to sPT
#pragma unroll
        for (int qt = 0; qt < 4; ++qt)
#pragma unroll
            for (int ct = 0; ct < 4; ++ct) {
                float p0 = exp2f(s[qt][ct][0]);
                float p1 = exp2f(s[qt][ct][1]);
                float p2 = exp2f(s[qt][ct][2]);
                float p3 = exp2f(s[qt][ct][3]);
                l4[qt] += (p0 + p1) + (p2 + p3);
                bf16x2 w0 = { (__bf16)p0, (__bf16)p1 };
                bf16x2 w1 = { (__bf16)p2, (__bf16)p3 };
                __bf16* pr = sQw + (qt * 16 + c) * 72 + ct * 16 + q * 4;
                *reinterpret_cast<bf16x2*>(pr)     = w0;
                *reinterpret_cast<bf16x2*>(pr + 2) = w1;
            }

        // O^T += V^T * P^T
#pragma unroll
        for (int ks = 0; ks < 2; ++ks) {
            const int so = ((ks * 4 + q) ^ (c & 7)) * 8;
            bf16x8 bp[4];
#pragma unroll
            for (int qt = 0; qt < 4; ++qt)
                bp[qt] = *reinterpret_cast<const bf16x8*>(sQw + (qt * 16 + c) * 72 + ks * 32 + q * 8);
#pragma unroll
            for (int nt = 0; nt < 4; ++nt) {
                bf16x8 av = *reinterpret_cast<const bf16x8*>(sV + (nt * 16 + c) * 64 + so);
#pragma unroll
                for (int qt = 0; qt < 4; ++qt)
                    accO[qt][nt] = __builtin_amdgcn_mfma_f32_16x16x32_bf16(av, bp[qt], accO[qt][nt], 0, 0, 0);
            }
        }
    }

    // epilogue: reduce l across the 4 lanes sharing a query column (lanes
    // c, 16+c, 32+c, 48+c each hold a disjoint quarter of the keys), then
    // O /= l, packed 8B stores
#pragma unroll
    for (int qt = 0; qt < 4; ++qt) {
        l4[qt] += __shfl_xor(l4[qt], 16, 64);
        l4[qt] += __shfl_xor(l4[qt], 32, 64);
    }
#pragma unroll
    for (int qt = 0; qt < 4; ++qt) {
        float inv = 1.0f / l4[qt];
        size_t rowb = (size_t)(b * SEQ_N + n0 + wave * 64 + qt * 16 + c) * ID + h * 64;
#pragma unroll
        for (int nt = 0; nt < 4; ++nt) {
            bf16x4 v = { (__bf16)(accO[qt][nt][0] * inv), (__bf16)(accO[qt][nt][1] * inv),
                         (__bf16)(accO[qt][nt][2] * inv), (__bf16)(accO[qt][nt][3] * inv) };
            *reinterpret_cast<bf16x4*>(&AO[rowb + nt * 16 + q * 4]) = v;
        }
    }
}

// ---------------------------------------------------------------------------
// Output projection (r9-exact): out = AO @ WoT^T + bias, fp32 out.
// 128x64 tiles (grid 640), wave 64x32, BK=64 dbuf, XOR swizzle.
// ---------------------------------------------------------------------------
__global__ __launch_bounds__(256)
void gemm_out(const __bf16* __restrict__ A, const __bf16* __restrict__ BT,
              const float* __restrict__ bias, float* __restrict__ C,
              int M, int N, int K) {
    __shared__ __attribute__((aligned(16))) __bf16 sA[2][128][64];
    __shared__ __attribute__((aligned(16))) __bf16 sB[2][64][64];

    const int t = threadIdx.x;
    const int wave = t >> 6, lane = t & 63;
    const int q = lane >> 4, c = lane & 15;
    const int wm = wave >> 1, wn = wave & 1;
    const int row0 = blockIdx.x * 128, col0 = blockIdx.y * 64;
    const int srow = lane >> 3, sch = lane & 7;
    const int fch = sch ^ srow;

    auto stage = [&](int buf, int k0) {
#pragma unroll
        for (int i = 0; i < 4; ++i) {
            int r = wave * 32 + i * 8;
            gload_lds16(A + (size_t)(row0 + r + srow) * K + k0 + fch * 8,
                        &sA[buf][r][0] + lane * 8);
        }
#pragma unroll
        for (int i = 0; i < 2; ++i) {
            int r = wave * 16 + i * 8;
            gload_lds16(BT + (size_t)(col0 + r + srow) * K + k0 + fch * 8,
                        &sB[buf][r][0] + lane * 8);
        }
    };

    f32x4 acc[4][2] = {};
    stage(0, 0);
    const int iters = K >> 6;
    for (int it = 0; it < iters; ++it) {
        const int p = it & 1;
        __syncthreads();
        if (it + 1 < iters) stage(p ^ 1, (it + 1) * 64);
#pragma unroll
        for (int ks = 0; ks < 2; ++ks) {
            const int so = ((ks * 4 + q) ^ (c & 7)) * 8;
            bf16x8 am[4], bn[2];
#pragma unroll
            for (int i = 0; i < 4; ++i)
                am[i] = *reinterpret_cast<const bf16x8*>(&sA[p][wm * 64 + i * 16 + c][0] + so);
#pragma unroll
            for (int j = 0; j < 2; ++j)
                bn[j] = *reinterpret_cast<const bf16x8*>(&sB[p][wn * 32 + j * 16 + c][0] + so);
#pragma unroll
            for (int i = 0; i < 4; ++i)
#pragma unroll
                for (int j = 0; j < 2; ++j)
                    acc[i][j] = __builtin_amdgcn_mfma_f32_16x16x32_bf16(bn[j], am[i], acc[i][j], 0, 0, 0);
        }
    }

#pragma unroll
    for (int i = 0; i < 4; ++i)
#pragma unroll
        for (int j = 0; j < 2; ++j) {
            int mrow = row0 + wm * 64 + i * 16 + c;
            int ncol = col0 + wn * 32 + j * 16 + q * 4;
            float4 v = { acc[i][j][0] + bias[ncol + 0],
                         acc[i][j][1] + bias[ncol + 1],
                         acc[i][j][2] + bias[ncol + 2],
                         acc[i][j][3] + bias[ncol + 3] };
            *reinterpret_cast<float4*>(&C[(size_t)mrow * N + ncol]) = v;
        }
}

// ---------------------------------------------------------------------------
extern "C" void kernel_launch(void* const* d_in, const int* in_sizes, int n_in,
                              void* d_out, int out_size, void* d_ws, size_t ws_size,
                              hipStream_t stream) {
    const float* x   = (const float*)d_in[0];
    const float* ctx = (const float*)d_in[1];
    const float* Wq  = (const float*)d_in[2];
    const float* Wk  = (const float*)d_in[3];
    const float* Wv  = (const float*)d_in[4];
    const float* Wo  = (const float*)d_in[5];
    const float* bo  = (const float*)d_in[6];
    float* out = (float*)d_out;

    char* ws = (char*)d_ws;
    __bf16* xb   = (__bf16*)(ws + 0);                 // 16384x320 (stays live)
    __bf16* ctxb = (__bf16*)(ws + 10485760);          // 4096x768
    __bf16* AO   = (__bf16*)(ws + 16777216);          // 16384x512
    __bf16* Kb   = (__bf16*)(ws + 33554432);          // 4096x512
    __bf16* Vt   = (__bf16*)(ws + 37748736);          // (32,64,1024)
    __bf16* WqT  = (__bf16*)(ws + 41943040);          // 512x320 (pre-scaled)
    __bf16* WkT  = (__bf16*)(ws + 42270720);          // 512x768 \ adjacent
    __bf16* WvT  = (__bf16*)(ws + 43057152);          // 512x768 / = 1024x768
    __bf16* WoT  = (__bf16*)(ws + 43843584);          // 320x512

    const int MX = BATCH * SEQ_N;   // 16384
    const int MC = BATCH * SEQ_M;   // 4096

    cvt_all<<<dim3(5184), dim3(256), 0, stream>>>(x, ctx, Wq, Wk, Wv, Wo,
                                                  xb, ctxb, WqT, WkT, WvT, WoT);

    // fused K+V projection (r9: 64x64 tiles; y<8 -> Kb, y>=8 -> Vt)
    gemm_kv<<<dim3(MC / 64, 16), dim3(256), 0, stream>>>(ctxb, WkT, Kb, Vt, MC, CD);

    // flash with fused Q-projection (256 queries/block)
    flash_attn<<<dim3(SEQ_N / 256, 32), dim3(256), 0, stream>>>(xb, WqT, Kb, Vt, AO);

    // output projection + bias (fp32 out)
    gemm_out<<<dim3(MX / 128, QD / 64), dim3(256), 0, stream>>>(AO, WoT, bo, out, MX, QD, ID);
}

// Round 13
// 174.955 us; speedup vs baseline: 1.3021x; 1.0539x over previous
//
#include <hip/hip_runtime.h>
#include <cmath>

// CrossAttention: B=4, N=4096, M=1024, QD=320, CD=768, ID=512, H=8, Dh=64
// fp32 I/O; bf16 MFMA internals, fp32 accumulate.
// r13 = r9-exact (flash/cvt/gemm_out) + gemm_kv retiled to 128x64 (gemm_out
// structure: 16 MFMA/wave/iter, BK=64 dbuf, 48 KB LDS).
constexpr int BATCH  = 4;
constexpr int SEQ_N  = 4096;
constexpr int SEQ_M  = 1024;
constexpr int QD     = 320;
constexpr int CD     = 768;
constexpr int ID     = 512;
constexpr float QFOLD = 0.125f * 1.44269504f;   // SCALE*log2e folded into Wq
constexpr float EK2F  = -8.0f * 1.44269504f;    // fixed softmax shift (log2 dom)

typedef __bf16 bf16x8 __attribute__((ext_vector_type(8)));
typedef __bf16 bf16x4 __attribute__((ext_vector_type(4)));
typedef __bf16 bf16x2 __attribute__((ext_vector_type(2)));
typedef float  f32x4  __attribute__((ext_vector_type(4)));

__device__ __forceinline__ void gload_lds16(const __bf16* g, __bf16* l) {
    __builtin_amdgcn_global_load_lds(
        (const __attribute__((address_space(1))) void*)g,
        (__attribute__((address_space(3))) void*)l, 16, 0, 0);
}

// ---------------------------------------------------------------------------
// One dispatch: fp32->bf16 for x/ctx (blocks 0..4095) + weight transpose/cvt
// (blocks 4096..5183).  Wq pre-scaled by QFOLD.  (r9-verified)
// ---------------------------------------------------------------------------
__global__ __launch_bounds__(256)
void cvt_all(const float* __restrict__ x, const float* __restrict__ ctx,
             const float* __restrict__ Wq, const float* __restrict__ Wk,
             const float* __restrict__ Wv, const float* __restrict__ Wo,
             __bf16* __restrict__ xb, __bf16* __restrict__ ctxb,
             __bf16* __restrict__ WqT, __bf16* __restrict__ WkT,
             __bf16* __restrict__ WvT, __bf16* __restrict__ WoT) {
    __shared__ float tile[32][33];
    int bid = blockIdx.x;
    if (bid < 4096) {
        constexpr int NX8 = SEQ_N * BATCH * QD / 8;   // 655360
        int i = bid * 256 + threadIdx.x;
        const float* s; __bf16* d; int j;
        if (i < NX8) { s = x; d = xb; j = i; }
        else         { s = ctx; d = ctxb; j = i - NX8; }
        const float4* sp = reinterpret_cast<const float4*>(s) + (size_t)j * 2;
        float4 a = sp[0], b = sp[1];
        bf16x8 o = { (__bf16)a.x, (__bf16)a.y, (__bf16)a.z, (__bf16)a.w,
                     (__bf16)b.x, (__bf16)b.y, (__bf16)b.z, (__bf16)b.w };
        reinterpret_cast<bf16x8*>(d)[j] = o;
        return;
    }
    int wb = bid - 4096;
    const float* W; __bf16* WT; int K, N, tid; float scl = 1.0f;
    if (wb < 160)      { W = Wq; WT = WqT; K = 320; N = 512; tid = wb; scl = QFOLD; }
    else if (wb < 544) { W = Wk; WT = WkT; K = 768; N = 512; tid = wb - 160; }
    else if (wb < 928) { W = Wv; WT = WvT; K = 768; N = 512; tid = wb - 544; }
    else               { W = Wo; WT = WoT; K = 512; N = 320; tid = wb - 928; }
    int kt = K / 32;
    int k0 = (tid % kt) * 32, n0 = (tid / kt) * 32;
    int tc = threadIdx.x & 31, tr = threadIdx.x >> 5;
#pragma unroll
    for (int p = 0; p < 4; ++p)
        tile[p * 8 + tr][tc] = W[(size_t)(k0 + p * 8 + tr) * N + n0 + tc];
    __syncthreads();
#pragma unroll
    for (int p = 0; p < 4; ++p)
        WT[(size_t)(n0 + p * 8 + tr) * K + k0 + tc] = (__bf16)(tile[tc][p * 8 + tr] * scl);
}

// ---------------------------------------------------------------------------
// KV projection (r13): C = ctxb @ [WkT|WvT]^T.  128x64 tiles (grid 512),
// wave tile 64x32 (16 MFMA/iter), BK=64 dbuf (48 KB), XOR chunk swizzle,
// operand-swapped MFMA.  y<8 -> Kb row-major packed bf16x4; y>=8 -> Vt
// (b,h,d,m) via per-wave 32d x 64m LDS transpose + 16B coalesced stores.
// ---------------------------------------------------------------------------
__global__ __launch_bounds__(256)
void gemm_kv(const __bf16* __restrict__ A, const __bf16* __restrict__ BT,
             __bf16* __restrict__ Kb, __bf16* __restrict__ Vt, int M, int K) {
    __shared__ __attribute__((aligned(16))) __bf16 sA[2][128][64];
    __shared__ __attribute__((aligned(16))) __bf16 sB[2][64][64];

    const int t = threadIdx.x;
    const int wave = t >> 6, lane = t & 63;
    const int q = lane >> 4, c = lane & 15;
    const int wm = wave >> 1, wn = wave & 1;
    const int row0 = blockIdx.x * 128, col0 = blockIdx.y * 64;
    const int srow = lane >> 3, sch = lane & 7;
    const int fch = sch ^ srow;

    auto stage = [&](int buf, int k0) {
#pragma unroll
        for (int i = 0; i < 4; ++i) {
            int r = wave * 32 + i * 8;
            gload_lds16(A + (size_t)(row0 + r + srow) * K + k0 + fch * 8,
                        &sA[buf][r][0] + lane * 8);
        }
#pragma unroll
        for (int i = 0; i < 2; ++i) {
            int r = wave * 16 + i * 8;
            gload_lds16(BT + (size_t)(col0 + r + srow) * K + k0 + fch * 8,
                        &sB[buf][r][0] + lane * 8);
        }
    };

    f32x4 acc[4][2] = {};   // [i: m-sub (64 rows)][j: d-sub (32 cols)]
    stage(0, 0);
    const int iters = K >> 6;   // 12
    for (int it = 0; it < iters; ++it) {
        const int p = it & 1;
        __syncthreads();
        if (it + 1 < iters) stage(p ^ 1, (it + 1) * 64);
#pragma unroll
        for (int ks = 0; ks < 2; ++ks) {
            const int so = ((ks * 4 + q) ^ (c & 7)) * 8;
            bf16x8 am[4], bn[2];
#pragma unroll
            for (int i = 0; i < 4; ++i)
                am[i] = *reinterpret_cast<const bf16x8*>(&sA[p][wm * 64 + i * 16 + c][0] + so);
#pragma unroll
            for (int j = 0; j < 2; ++j)
                bn[j] = *reinterpret_cast<const bf16x8*>(&sB[p][wn * 32 + j * 16 + c][0] + so);
#pragma unroll
            for (int i = 0; i < 4; ++i)
#pragma unroll
                for (int j = 0; j < 2; ++j)
                    acc[i][j] = __builtin_amdgcn_mfma_f32_16x16x32_bf16(bn[j], am[i], acc[i][j], 0, 0, 0);
        }
    }

    if (blockIdx.y < 8) {
        // K half: lane holds row m = ...+c, 4 consecutive cols -> packed 8B
#pragma unroll
        for (int i = 0; i < 4; ++i)
#pragma unroll
            for (int j = 0; j < 2; ++j) {
                int mrow = row0 + wm * 64 + i * 16 + c;
                int ncol = col0 + wn * 32 + j * 16 + q * 4;
                bf16x4 v = { (__bf16)acc[i][j][0], (__bf16)acc[i][j][1],
                             (__bf16)acc[i][j][2], (__bf16)acc[i][j][3] };
                *reinterpret_cast<bf16x4*>(&Kb[(size_t)mrow * 512 + ncol]) = v;
            }
    } else {
        // V half: per-wave transpose (32 d x 64 m) through LDS, 16B stores
        __syncthreads();   // all K-loop LDS reads done; reuse sA region
        __bf16* ldsT = ((__bf16*)sA) + wave * 2304;   // [32][72]
#pragma unroll
        for (int i = 0; i < 4; ++i)
#pragma unroll
            for (int j = 0; j < 2; ++j)
#pragma unroll
                for (int r = 0; r < 4; ++r)
                    ldsT[(j * 16 + q * 4 + r) * 72 + i * 16 + c] = (__bf16)acc[i][j][r];
        __syncthreads();   // (within-wave ordering suffices, but keep simple)
        int b = row0 >> 10;
        int mg = (row0 & 1023) + wm * 64;
        int dbase = col0 - 512 + wn * 32;
#pragma unroll
        for (int it2 = 0; it2 < 4; ++it2) {
            int dloc = it2 * 8 + (lane >> 3);   // 0..31
            int ch = lane & 7;                  // 8 m-chunks of 8 elems
            int dg = dbase + dloc;
            int h = dg >> 6, d = dg & 63;
            *reinterpret_cast<bf16x8*>(
                Vt + (((size_t)((b * 8 + h) * 64 + d)) << 10) + mg + ch * 8) =
                *reinterpret_cast<const bf16x8*>(&ldsT[dloc * 72 + ch * 8]);
        }
    }
}

// ---------------------------------------------------------------------------
// Flash attention (r9-exact): block = (b,h) x 256 queries; 4 waves x 64
// queries (qt=4).  Fused Q-projection prologue.  64-key tiles, dbuf sK/sV
// (one barrier/tile).  S^T = K*Q^T with EK2F in MFMA C-init; p = exp2(s);
// l via ones-MFMA (accumulator-file resident — VALU l spills, r12).
// LDS: 16384 (KV dbuf) + 18432 (sPT) elems = 69632 B -> 2 blocks/CU (= grid).
// ---------------------------------------------------------------------------
__global__ __launch_bounds__(256, 2)
void flash_attn(const __bf16* __restrict__ xb, const __bf16* __restrict__ WqT,
                const __bf16* __restrict__ Kb, const __bf16* __restrict__ Vt,
                __bf16* __restrict__ AO) {
    __shared__ __attribute__((aligned(16))) __bf16 smem[34816];
    __bf16* sPT = smem + 16384;          // [4 waves][64][72]

    const int t = threadIdx.x;
    const int wave = t >> 6, lane = t & 63;
    const int q = lane >> 4, c = lane & 15;
    const int bh = blockIdx.y;
    const int b = bh >> 3, h = bh & 7;
    const int n0 = blockIdx.x * 256;
    const int srow = lane >> 3, sch = lane & 7;
    const int fch = sch ^ srow;

    // ---- Prologue: Q^T[64 d][256 q] = WqT_h @ xb^T, 5 staged BK=64 iters --
    f32x4 accQ[4][4] = {};   // [dt][qt]
    {
        __bf16* sX = smem;
        __bf16* sW = smem + 16384;
        for (int k0 = 0; k0 < QD; k0 += 64) {
            __syncthreads();
#pragma unroll
            for (int i = 0; i < 8; ++i) {
                int r = wave * 64 + i * 8;
                gload_lds16(xb + (size_t)(b * SEQ_N + n0 + r + srow) * QD + k0 + fch * 8,
                            sX + r * 64 + lane * 8);
            }
#pragma unroll
            for (int i = 0; i < 2; ++i) {
                int r = wave * 16 + i * 8;
                gload_lds16(WqT + (size_t)(h * 64 + r + srow) * QD + k0 + fch * 8,
                            sW + r * 64 + lane * 8);
            }
            __syncthreads();
#pragma unroll
            for (int ks = 0; ks < 2; ++ks) {
                const int so = ((ks * 4 + q) ^ (c & 7)) * 8;
                bf16x8 aw[4], bx[4];
#pragma unroll
                for (int dt = 0; dt < 4; ++dt)
                    aw[dt] = *reinterpret_cast<const bf16x8*>(sW + (dt * 16 + c) * 64 + so);
#pragma unroll
                for (int qt = 0; qt < 4; ++qt)
                    bx[qt] = *reinterpret_cast<const bf16x8*>(sX + (wave * 64 + qt * 16 + c) * 64 + so);
#pragma unroll
                for (int dt = 0; dt < 4; ++dt)
#pragma unroll
                    for (int qt = 0; qt < 4; ++qt)
                        accQ[dt][qt] = __builtin_amdgcn_mfma_f32_16x16x32_bf16(aw[dt], bx[qt], accQ[dt][qt], 0, 0, 0);
            }
        }
    }
    __syncthreads();   // all prologue LDS reads consumed before region reuse

    // C-layout -> per-wave LDS slice -> B-layout register frags
    __bf16* sQw = sPT + wave * 4608;     // [64][72]
#pragma unroll
    for (int dt = 0; dt < 4; ++dt)
#pragma unroll
        for (int qt = 0; qt < 4; ++qt) {
            bf16x2 w0 = { (__bf16)accQ[dt][qt][0], (__bf16)accQ[dt][qt][1] };
            bf16x2 w1 = { (__bf16)accQ[dt][qt][2], (__bf16)accQ[dt][qt][3] };
            __bf16* pr = sQw + (qt * 16 + c) * 72 + dt * 16 + q * 4;
            *reinterpret_cast<bf16x2*>(pr)     = w0;
            *reinterpret_cast<bf16x2*>(pr + 2) = w1;
        }
    bf16x8 aq[4][2];
#pragma unroll
    for (int qt = 0; qt < 4; ++qt)
#pragma unroll
        for (int ks = 0; ks < 2; ++ks)
            aq[qt][ks] = *reinterpret_cast<const bf16x8*>(sQw + (qt * 16 + c) * 72 + ks * 32 + q * 8);

    // ---- Main loop: dbuf KV, one barrier per tile -------------------------
    auto stageKV = [&](int buf, int m0) {
        __bf16* sK = smem + buf * 8192;
        __bf16* sV = smem + buf * 8192 + 4096;
#pragma unroll
        for (int i = 0; i < 2; ++i) {
            int r = wave * 16 + i * 8;
            gload_lds16(Kb + (size_t)(b * SEQ_M + m0 + r + srow) * ID + h * 64 + fch * 8,
                        sK + r * 64 + lane * 8);
            gload_lds16(Vt + (((size_t)((b * 8 + h) * 64 + r + srow)) << 10) + m0 + fch * 8,
                        sV + r * 64 + lane * 8);
        }
    };

    const bf16x8 ONES = { (__bf16)1.0f, (__bf16)1.0f, (__bf16)1.0f, (__bf16)1.0f,
                          (__bf16)1.0f, (__bf16)1.0f, (__bf16)1.0f, (__bf16)1.0f };
    f32x4 accO[4][4] = {};   // [qt][nt]
    f32x4 accL[4] = {};      // [qt]

    stageKV(0, 0);
    constexpr int TILES = SEQ_M / 64;   // 16
    for (int mt = 0; mt < TILES; ++mt) {
        const int p = mt & 1;
        __syncthreads();                 // buf p staged (barrier drains vmcnt)
        if (mt + 1 < TILES) stageKV(p ^ 1, (mt + 1) * 64);
        const __bf16* sK = smem + p * 8192;
        const __bf16* sV = smem + p * 8192 + 4096;

        // S^T = K * Q^T + EK2F (shift folded into C-init)
        f32x4 s[4][4];
#pragma unroll
        for (int qt = 0; qt < 4; ++qt)
#pragma unroll
            for (int ct = 0; ct < 4; ++ct)
                s[qt][ct] = f32x4{ EK2F, EK2F, EK2F, EK2F };
#pragma unroll
        for (int ks = 0; ks < 2; ++ks) {
            const int so = ((ks * 4 + q) ^ (c & 7)) * 8;
#pragma unroll
            for (int ct = 0; ct < 4; ++ct) {
                bf16x8 ak = *reinterpret_cast<const bf16x8*>(sK + (ct * 16 + c) * 64 + so);
#pragma unroll
                for (int qt = 0; qt < 4; ++qt)
                    s[qt][ct] = __builtin_amdgcn_mfma_f32_16x16x32_bf16(ak, aq[qt][ks], s[qt][ct], 0, 0, 0);
            }
        }

        // p = exp2(s); packed-pair writes to per-wave sPT
#pragma unroll
        for (int qt = 0; qt < 4; ++qt)
#pragma unroll
            for (int ct = 0; ct < 4; ++ct) {
                float p0 = exp2f(s[qt][ct][0]);
                float p1 = exp2f(s[qt][ct][1]);
                float p2 = exp2f(s[qt][ct][2]);
                float p3 = exp2f(s[qt][ct][3]);
                bf16x2 w0 = { (__bf16)p0, (__bf16)p1 };
                bf16x2 w1 = { (__bf16)p2, (__bf16)p3 };
                __bf16* pr = sQw + (qt * 16 + c) * 72 + ct * 16 + q * 4;
                *reinterpret_cast<bf16x2*>(pr)     = w0;
                *reinterpret_cast<bf16x2*>(pr + 2) = w1;
            }

        // O^T += V^T * P^T ; l += ones * P^T
#pragma unroll
        for (int ks = 0; ks < 2; ++ks) {
            const int so = ((ks * 4 + q) ^ (c & 7)) * 8;
            bf16x8 bp[4];
#pragma unroll
            for (int qt = 0; qt < 4; ++qt)
                bp[qt] = *reinterpret_cast<const bf16x8*>(sQw + (qt * 16 + c) * 72 + ks * 32 + q * 8);
#pragma unroll
            for (int qt = 0; qt < 4; ++qt)
                accL[qt] = __builtin_amdgcn_mfma_f32_16x16x32_bf16(ONES, bp[qt], accL[qt], 0, 0, 0);
#pragma unroll
            for (int nt = 0; nt < 4; ++nt) {
                bf16x8 av = *reinterpret_cast<const bf16x8*>(sV + (nt * 16 + c) * 64 + so);
#pragma unroll
                for (int qt = 0; qt < 4; ++qt)
                    accO[qt][nt] = __builtin_amdgcn_mfma_f32_16x16x32_bf16(av, bp[qt], accO[qt][nt], 0, 0, 0);
            }
        }
    }

    // epilogue: O /= l, packed 8B stores
#pragma unroll
    for (int qt = 0; qt < 4; ++qt) {
        float inv = 1.0f / accL[qt][0];
        size_t rowb = (size_t)(b * SEQ_N + n0 + wave * 64 + qt * 16 + c) * ID + h * 64;
#pragma unroll
        for (int nt = 0; nt < 4; ++nt) {
            bf16x4 v = { (__bf16)(accO[qt][nt][0] * inv), (__bf16)(accO[qt][nt][1] * inv),
                         (__bf16)(accO[qt][nt][2] * inv), (__bf16)(accO[qt][nt][3] * inv) };
            *reinterpret_cast<bf16x4*>(&AO[rowb + nt * 16 + q * 4]) = v;
        }
    }
}

// ---------------------------------------------------------------------------
// Output projection (r9-exact): out = AO @ WoT^T + bias, fp32 out.
// 128x64 tiles (grid 640), wave 64x32, BK=64 dbuf, XOR swizzle.
// ---------------------------------------------------------------------------
__global__ __launch_bounds__(256)
void gemm_out(const __bf16* __restrict__ A, const __bf16* __restrict__ BT,
              const float* __restrict__ bias, float* __restrict__ C,
              int M, int N, int K) {
    __shared__ __attribute__((aligned(16))) __bf16 sA[2][128][64];
    __shared__ __attribute__((aligned(16))) __bf16 sB[2][64][64];

    const int t = threadIdx.x;
    const int wave = t >> 6, lane = t & 63;
    const int q = lane >> 4, c = lane & 15;
    const int wm = wave >> 1, wn = wave & 1;
    const int row0 = blockIdx.x * 128, col0 = blockIdx.y * 64;
    const int srow = lane >> 3, sch = lane & 7;
    const int fch = sch ^ srow;

    auto stage = [&](int buf, int k0) {
#pragma unroll
        for (int i = 0; i < 4; ++i) {
            int r = wave * 32 + i * 8;
            gload_lds16(A + (size_t)(row0 + r + srow) * K + k0 + fch * 8,
                        &sA[buf][r][0] + lane * 8);
        }
#pragma unroll
        for (int i = 0; i < 2; ++i) {
            int r = wave * 16 + i * 8;
            gload_lds16(BT + (size_t)(col0 + r + srow) * K + k0 + fch * 8,
                        &sB[buf][r][0] + lane * 8);
        }
    };

    f32x4 acc[4][2] = {};
    stage(0, 0);
    const int iters = K >> 6;
    for (int it = 0; it < iters; ++it) {
        const int p = it & 1;
        __syncthreads();
        if (it + 1 < iters) stage(p ^ 1, (it + 1) * 64);
#pragma unroll
        for (int ks = 0; ks < 2; ++ks) {
            const int so = ((ks * 4 + q) ^ (c & 7)) * 8;
            bf16x8 am[4], bn[2];
#pragma unroll
            for (int i = 0; i < 4; ++i)
                am[i] = *reinterpret_cast<const bf16x8*>(&sA[p][wm * 64 + i * 16 + c][0] + so);
#pragma unroll
            for (int j = 0; j < 2; ++j)
                bn[j] = *reinterpret_cast<const bf16x8*>(&sB[p][wn * 32 + j * 16 + c][0] + so);
#pragma unroll
            for (int i = 0; i < 4; ++i)
#pragma unroll
                for (int j = 0; j < 2; ++j)
                    acc[i][j] = __builtin_amdgcn_mfma_f32_16x16x32_bf16(bn[j], am[i], acc[i][j], 0, 0, 0);
        }
    }

#pragma unroll
    for (int i = 0; i < 4; ++i)
#pragma unroll
        for (int j = 0; j < 2; ++j) {
            int mrow = row0 + wm * 64 + i * 16 + c;
            int ncol = col0 + wn * 32 + j * 16 + q * 4;
            float4 v = { acc[i][j][0] + bias[ncol + 0],
                         acc[i][j][1] + bias[ncol + 1],
                         acc[i][j][2] + bias[ncol + 2],
                         acc[i][j][3] + bias[ncol + 3] };
            *reinterpret_cast<float4*>(&C[(size_t)mrow * N + ncol]) = v;
        }
}

// ---------------------------------------------------------------------------
extern "C" void kernel_launch(void* const* d_in, const int* in_sizes, int n_in,
                              void* d_out, int out_size, void* d_ws, size_t ws_size,
                              hipStream_t stream) {
    const float* x   = (const float*)d_in[0];
    const float* ctx = (const float*)d_in[1];
    const float* Wq  = (const float*)d_in[2];
    const float* Wk  = (const float*)d_in[3];
    const float* Wv  = (const float*)d_in[4];
    const float* Wo  = (const float*)d_in[5];
    const float* bo  = (const float*)d_in[6];
    float* out = (float*)d_out;

    char* ws = (char*)d_ws;
    __bf16* xb   = (__bf16*)(ws + 0);                 // 16384x320 (stays live)
    __bf16* ctxb = (__bf16*)(ws + 10485760);          // 4096x768
    __bf16* AO   = (__bf16*)(ws + 16777216);          // 16384x512
    __bf16* Kb   = (__bf16*)(ws + 33554432);          // 4096x512
    __bf16* Vt   = (__bf16*)(ws + 37748736);          // (32,64,1024)
    __bf16* WqT  = (__bf16*)(ws + 41943040);          // 512x320 (pre-scaled)
    __bf16* WkT  = (__bf16*)(ws + 42270720);          // 512x768 \ adjacent
    __bf16* WvT  = (__bf16*)(ws + 43057152);          // 512x768 / = 1024x768
    __bf16* WoT  = (__bf16*)(ws + 43843584);          // 320x512

    const int MX = BATCH * SEQ_N;   // 16384
    const int MC = BATCH * SEQ_M;   // 4096

    cvt_all<<<dim3(5184), dim3(256), 0, stream>>>(x, ctx, Wq, Wk, Wv, Wo,
                                                  xb, ctxb, WqT, WkT, WvT, WoT);

    // fused K+V projection, 128x64 tiles (y<8 -> Kb, y>=8 -> Vt transposed)
    gemm_kv<<<dim3(MC / 128, 16), dim3(256), 0, stream>>>(ctxb, WkT, Kb, Vt, MC, CD);

    // flash with fused Q-projection (256 queries/block)
    flash_attn<<<dim3(SEQ_N / 256, 32), dim3(256), 0, stream>>>(xb, WqT, Kb, Vt, AO);

    // output projection + bias (fp32 out)
    gemm_out<<<dim3(MX / 128, QD / 64), dim3(256), 0, stream>>>(AO, WoT, bo, out, MX, QD, ID);
}